// Round 1
// baseline (203.160 us; speedup 1.0000x reference)
//
#include <hip/hip_runtime.h>

#define NBINS   4096
#define THREADS 256
#define BLOCKS  1024

// Per-element processing shared by vector body and tail.
__device__ __forceinline__ void process_elem(
    float g, float p,
    unsigned int& posc, unsigned int& ignc, float& psum_local,
    unsigned int* hc, float* hs)
{
    // torch-style BCE with log clamp at -100:
    // loss = -(g*max(log p,-100) + (1-g)*max(log(1-p),-100))
    //      =   g*min(-log p,100) + (1-g)*min(-log(1-p),100)
    float nlp = fminf(-__logf(p), 100.0f);
    float nlq = fminf(-__logf(1.0f - p), 100.0f);
    float loss = g * nlp + (1.0f - g) * nlq;

    if (g >= 0.9f) {                 // hard positive
        posc++;
        psum_local += loss;
    } else if (g >= 0.8f) {          // ignore band
        ignc++;
    } else {                         // negative candidate
        // bin by float bits: monotone for loss >= 0; guard -0.0 / NaN to bin 0
        unsigned int b = (loss > 0.0f) ? (__float_as_uint(loss) >> 19) : 0u;
        if (b > NBINS - 1) b = NBINS - 1;
        atomicAdd(&hc[b], 1u);
        atomicAdd(&hs[b], loss);
    }
}

__global__ __launch_bounds__(THREADS) void pass1(
    const float* __restrict__ gt, const float* __restrict__ pred,
    unsigned int* __restrict__ counts, float* __restrict__ sums,
    unsigned int* __restrict__ posIgn, double* __restrict__ psum,
    int n4, int nTail, long long tailBase)
{
    __shared__ unsigned int hc[NBINS];
    __shared__ float        hs[NBINS];
    for (int i = threadIdx.x; i < NBINS; i += THREADS) { hc[i] = 0u; hs[i] = 0.0f; }
    __syncthreads();

    unsigned int posc = 0, ignc = 0;
    float ps = 0.0f;

    const float4* g4p = (const float4*)gt;
    const float4* p4p = (const float4*)pred;
    const int stride = gridDim.x * blockDim.x;
    for (int i = blockIdx.x * blockDim.x + threadIdx.x; i < n4; i += stride) {
        float4 g4 = g4p[i];
        float4 p4 = p4p[i];
        process_elem(g4.x, p4.x, posc, ignc, ps, hc, hs);
        process_elem(g4.y, p4.y, posc, ignc, ps, hc, hs);
        process_elem(g4.z, p4.z, posc, ignc, ps, hc, hs);
        process_elem(g4.w, p4.w, posc, ignc, ps, hc, hs);
    }
    // scalar tail (N % 4)
    if (blockIdx.x == 0 && threadIdx.x < nTail) {
        long long i = tailBase + threadIdx.x;
        process_elem(gt[i], pred[i], posc, ignc, ps, hc, hs);
    }

    __syncthreads();
    // flush per-block histogram (skip empty bins)
    for (int i = threadIdx.x; i < NBINS; i += THREADS) {
        unsigned int c = hc[i];
        if (c) {
            atomicAdd(&counts[i], c);
            atomicAdd(&sums[i], hs[i]);
        }
    }

    // wave-64 reduce scalars, one atomic per wave
    double pd = (double)ps;
    for (int off = 32; off > 0; off >>= 1) {
        posc += __shfl_down(posc, off);
        ignc += __shfl_down(ignc, off);
        pd   += __shfl_down(pd, off);
    }
    if ((threadIdx.x & 63) == 0) {
        if (posc) atomicAdd(&posIgn[0], posc);
        if (ignc) atomicAdd(&posIgn[1], ignc);
        atomicAdd(psum, pd);
    }
}

__global__ __launch_bounds__(256) void finalize(
    const unsigned int* __restrict__ counts, const float* __restrict__ sums,
    const unsigned int* __restrict__ posIgn, const double* __restrict__ psum,
    float* __restrict__ out)
{
    __shared__ unsigned long long scnt[256];
    __shared__ double             ssum[256];
    __shared__ int                s_chunk;
    __shared__ double             s_topk;

    const int t = threadIdx.x;
    const int base = t * (NBINS / 256);   // 16 bins per thread

    unsigned long long c = 0; double s = 0.0;
    #pragma unroll
    for (int i = 0; i < NBINS / 256; ++i) {
        c += counts[base + i];
        s += (double)sums[base + i];
    }
    scnt[t] = c; ssum[t] = s;
    if (t == 0) { s_chunk = -1; s_topk = 0.0; }
    __syncthreads();

    // inclusive suffix scan over 256 chunks (Hillis-Steele)
    for (int off = 1; off < 256; off <<= 1) {
        unsigned long long cv = (t + off < 256) ? scnt[t + off] : 0ull;
        double             sv = (t + off < 256) ? ssum[t + off] : 0.0;
        __syncthreads();
        scnt[t] += cv; ssum[t] += sv;
        __syncthreads();
    }

    const unsigned int pos = posIgn[0];
    const unsigned long long total = scnt[0];   // exact negative-candidate count

    // k = floor(min(max(pos,1)*3.0, neg)) in f32, mirroring reference
    float kf = fminf(fmaxf((float)pos, 1.0f) * 3.0f, (float)total);
    long long k = (long long)floorf(kf);

    unsigned long long Sincl = scnt[t];
    unsigned long long Sexcl = (t < 255) ? scnt[t + 1] : 0ull;
    double SexclSum          = (t < 255) ? ssum[t + 1] : 0.0;

    if (k > 0 && Sexcl < (unsigned long long)k && Sincl >= (unsigned long long)k) {
        // this thread's chunk contains the k-th largest value
        double topk = SexclSum;
        unsigned long long need = (unsigned long long)k - Sexcl;
        for (int i = (NBINS / 256) - 1; i >= 0 && need > 0; --i) {
            int b = base + i;
            unsigned long long cb = counts[b];
            if (!cb) continue;
            double sb = (double)sums[b];
            if (cb <= need) {
                topk += sb;
                need -= cb;
            } else {
                // partial bin: uniform-within-bin model anchored at measured mean
                float lo = __uint_as_float((unsigned)b << 19);
                float hi = (b + 1 < NBINS) ? __uint_as_float((unsigned)(b + 1) << 19) : lo;
                double w = (double)hi - (double)lo;
                double n = (double)cb;
                double r = (double)need;
                double mean = sb / n;
                topk += r * (mean + 0.5 * w * (1.0 - r / n));
                need = 0;
            }
        }
        s_topk = topk;
        s_chunk = t;
    }
    __syncthreads();

    if (t == 0) {
        double topk = (s_chunk >= 0) ? s_topk : 0.0;
        float denf = (float)pos + (float)k;   // f32 like reference
        denf += 1e-4f;
        double res = (3.0 * (*psum) + topk) / (double)denf;
        out[0] = (float)res;
    }
}

extern "C" void kernel_launch(void* const* d_in, const int* in_sizes, int n_in,
                              void* d_out, int out_size, void* d_ws, size_t ws_size,
                              hipStream_t stream) {
    const float* gt   = (const float*)d_in[0];
    const float* pred = (const float*)d_in[1];
    float* out = (float*)d_out;

    // workspace layout: [0,8) double psum | [8,16) u32 pos,ign | counts | sums
    double*       psum   = (double*)d_ws;
    unsigned int* posIgn = (unsigned int*)((char*)d_ws + 8);
    unsigned int* counts = (unsigned int*)((char*)d_ws + 16);
    float*        sums   = (float*)((char*)d_ws + 16 + NBINS * sizeof(unsigned int));

    size_t zbytes = 16 + (size_t)NBINS * 8;
    hipMemsetAsync(d_ws, 0, zbytes, stream);

    long long n = (long long)in_sizes[0];
    int n4 = (int)(n >> 2);
    int nTail = (int)(n & 3);
    long long tailBase = (long long)n4 * 4;

    pass1<<<dim3(BLOCKS), dim3(THREADS), 0, stream>>>(
        gt, pred, counts, sums, posIgn, psum, n4, nTail, tailBase);
    finalize<<<dim3(1), dim3(256), 0, stream>>>(counts, sums, posIgn, psum, out);
}

// Round 2
// 92.692 us; speedup vs baseline: 2.1918x; 2.1918x over previous
//
#include <hip/hip_runtime.h>

#define NBINS    2048          // float bits >> 20 : 8 exp + 3 mantissa bits
#define REPL     4             // per-wave-lane-group replicas to cut same-address serialization
#define THREADS  256
#define BLOCKS   512           // 2 blocks/CU resident (64 KB LDS each)
#define FIXSH    20            // fixed-point scale 2^20 for loss sums
#define CNTSH    44            // count lives in bits [44,64)

__device__ __forceinline__ void process_elem(
    float g, float p,
    unsigned int& posc, float& ps,
    unsigned long long* hist, unsigned int repl)
{
    // torch-style BCE with log clamp at -100:
    // loss = g*min(-log p,100) + (1-g)*min(-log(1-p),100)
    float nlp = fminf(-__logf(p), 100.0f);
    float nlq = fminf(-__logf(1.0f - p), 100.0f);
    float loss = fmaf(g, nlp - nlq, nlq);     // g*nlp + (1-g)*nlq

    bool isPos = (g >= 0.9f);
    bool isNeg = (g < 0.8f);
    posc += isPos;
    if (isPos) ps += loss;
    if (isNeg) {
        unsigned int b = 0;
        if (loss > 0.0f) {                     // guard -0.0 / nonpositive
            b = __float_as_uint(loss) >> 20;
            if (b > NBINS - 1) b = NBINS - 1;
        }
        // fixed-point quantize (loss <= 100 -> fits u32); pack count|sum
        unsigned long long q =
            (unsigned long long)(unsigned int)(fmaf(loss, 1048576.0f, 0.5f));
        atomicAdd(&hist[(b << 2) | repl], (1ull << CNTSH) | q);
    }
}

__global__ __launch_bounds__(THREADS) void pass1(
    const float* __restrict__ gt, const float* __restrict__ pred,
    unsigned int* __restrict__ counts, unsigned long long* __restrict__ sums,
    unsigned int* __restrict__ posCnt, double* __restrict__ psum,
    int n4, int nTail, long long tailBase)
{
    __shared__ unsigned long long hist[NBINS * REPL];
    for (int i = threadIdx.x; i < NBINS * REPL; i += THREADS) hist[i] = 0ull;
    __syncthreads();

    unsigned int posc = 0;
    float ps = 0.0f;
    const unsigned int repl = threadIdx.x & (REPL - 1);

    const float4* g4p = (const float4*)gt;
    const float4* p4p = (const float4*)pred;
    const int stride = gridDim.x * blockDim.x;
    for (int i = blockIdx.x * blockDim.x + threadIdx.x; i < n4; i += stride) {
        float4 g4 = g4p[i];
        float4 p4 = p4p[i];
        process_elem(g4.x, p4.x, posc, ps, hist, repl);
        process_elem(g4.y, p4.y, posc, ps, hist, repl);
        process_elem(g4.z, p4.z, posc, ps, hist, repl);
        process_elem(g4.w, p4.w, posc, ps, hist, repl);
    }
    if (blockIdx.x == 0 && threadIdx.x < nTail) {
        long long i = tailBase + threadIdx.x;
        process_elem(gt[i], pred[i], posc, ps, hist, repl);
    }

    __syncthreads();
    // flush: fold 4 replicas (packed fields add safely: total sum < 2^44,
    // total count < 2^20), then one u32 + one u64 global atomic per active bin
    for (int b = threadIdx.x; b < NBINS; b += THREADS) {
        unsigned long long v = hist[(b << 2) | 0] + hist[(b << 2) | 1]
                             + hist[(b << 2) | 2] + hist[(b << 2) | 3];
        if (v) {
            atomicAdd(&counts[b], (unsigned int)(v >> CNTSH));
            atomicAdd(&sums[b],   v & ((1ull << CNTSH) - 1));
        }
    }

    // wave-64 reduce scalars, one atomic per wave
    double pd = (double)ps;
    for (int off = 32; off > 0; off >>= 1) {
        posc += __shfl_down(posc, off);
        pd   += __shfl_down(pd, off);
    }
    if ((threadIdx.x & 63) == 0) {
        if (posc) atomicAdd(posCnt, posc);
        atomicAdd(psum, pd);
    }
}

__global__ __launch_bounds__(256) void finalize(
    const unsigned int* __restrict__ counts,
    const unsigned long long* __restrict__ sums,
    const unsigned int* __restrict__ posCnt, const double* __restrict__ psum,
    float* __restrict__ out)
{
    __shared__ unsigned long long scnt[256];
    __shared__ double             ssum[256];
    __shared__ int                s_chunk;
    __shared__ double             s_topk;

    const int t = threadIdx.x;
    const int BPT = NBINS / 256;          // 8 bins per thread
    const int base = t * BPT;
    const double INVFIX = 1.0 / 1048576.0;

    unsigned long long c = 0; double s = 0.0;
    #pragma unroll
    for (int i = 0; i < BPT; ++i) {
        c += counts[base + i];
        s += (double)sums[base + i] * INVFIX;
    }
    scnt[t] = c; ssum[t] = s;
    if (t == 0) { s_chunk = -1; s_topk = 0.0; }
    __syncthreads();

    // inclusive suffix scan over 256 chunks
    for (int off = 1; off < 256; off <<= 1) {
        unsigned long long cv = (t + off < 256) ? scnt[t + off] : 0ull;
        double             sv = (t + off < 256) ? ssum[t + off] : 0.0;
        __syncthreads();
        scnt[t] += cv; ssum[t] += sv;
        __syncthreads();
    }

    const unsigned int pos = posCnt[0];
    const unsigned long long total = scnt[0];   // exact negative count

    // k = floor(min(max(pos,1)*3.0, neg)) in f32, mirroring reference
    float kf = fminf(fmaxf((float)pos, 1.0f) * 3.0f, (float)total);
    long long k = (long long)floorf(kf);

    unsigned long long Sincl = scnt[t];
    unsigned long long Sexcl = (t < 255) ? scnt[t + 1] : 0ull;
    double SexclSum          = (t < 255) ? ssum[t + 1] : 0.0;

    if (k > 0 && Sexcl < (unsigned long long)k && Sincl >= (unsigned long long)k) {
        double topk = SexclSum;
        unsigned long long need = (unsigned long long)k - Sexcl;
        for (int i = BPT - 1; i >= 0 && need > 0; --i) {
            int b = base + i;
            unsigned long long cb = counts[b];
            if (!cb) continue;
            double sb = (double)sums[b] * INVFIX;
            if (cb <= need) {
                topk += sb;
                need -= cb;
            } else {
                // partial bin: uniform-within-bin model anchored at bin mean
                float lo = __uint_as_float((unsigned)b << 20);
                float hi = (b + 1 < NBINS) ? __uint_as_float((unsigned)(b + 1) << 20) : lo;
                double w = (double)hi - (double)lo;
                double n = (double)cb;
                double r = (double)need;
                double mean = sb / n;
                topk += r * (mean + 0.5 * w * (1.0 - r / n));
                need = 0;
            }
        }
        s_topk = topk;
        s_chunk = t;
    }
    __syncthreads();

    if (t == 0) {
        double topk = (s_chunk >= 0) ? s_topk : 0.0;
        float denf = (float)pos + (float)k;
        denf += 1e-4f;
        double res = (3.0 * (*psum) + topk) / (double)denf;
        out[0] = (float)res;
    }
}

extern "C" void kernel_launch(void* const* d_in, const int* in_sizes, int n_in,
                              void* d_out, int out_size, void* d_ws, size_t ws_size,
                              hipStream_t stream) {
    const float* gt   = (const float*)d_in[0];
    const float* pred = (const float*)d_in[1];
    float* out = (float*)d_out;

    // ws: [0,8) double psum | [8,12) u32 pos | pad | [16,16+8K) u32 counts
    //     | [16+8K, 16+8K+16K) u64 sums
    double*             psum   = (double*)d_ws;
    unsigned int*       posCnt = (unsigned int*)((char*)d_ws + 8);
    unsigned int*       counts = (unsigned int*)((char*)d_ws + 16);
    unsigned long long* sums   = (unsigned long long*)((char*)d_ws + 16 + NBINS * sizeof(unsigned int));

    size_t zbytes = 16 + (size_t)NBINS * (sizeof(unsigned int) + sizeof(unsigned long long));
    hipMemsetAsync(d_ws, 0, zbytes, stream);

    long long n = (long long)in_sizes[0];
    int n4 = (int)(n >> 2);
    int nTail = (int)(n & 3);
    long long tailBase = (long long)n4 * 4;

    pass1<<<dim3(BLOCKS), dim3(THREADS), 0, stream>>>(
        gt, pred, counts, sums, posCnt, psum, n4, nTail, tailBase);
    finalize<<<dim3(1), dim3(256), 0, stream>>>(counts, sums, posCnt, psum, out);
}